// Round 10
// baseline (185.283 us; speedup 1.0000x reference)
//
#include <hip/hip_runtime.h>

// B=4096, D=64, DM=256, K=32, KA=16, S=50
#define PITERS 6

// ---- workspace layout (float offsets) ----
// stage-1 (dead after k1b):
#define OFF_XQ   0        // [65][256]  Zf@Wq
#define OFF_KL   16640    // [65][256]  Lf@Wk
#define OFF_KC   33280    // [65][256]  Cf@Wk
#define OFF_VL   49920    // [65][256]  Lf@Wv
#define OFF_VC   66560    // [65][256]  Cf@Wv
#define OFF_KE   83200    // [48][256]  EMB@Wk
#define OFF_VE   95488    // [48][256]  EMB@Wv
#define OFF_M    107776   // [256][64]  Wo@fW
// stage-2 (k2 inputs):
#define OFF_PLm  128256   // [65][64]
#define OFF_PLc  132416   // [72]
#define OFF_PCm  132488   // [65][64]
#define OFF_PCc  136648   // [72]
#define OFF_CK2  136720   // [65][48]
#define OFF_ANCT 139840   // [64][48]
#define OFF_ANCN 142912   // [64]
#define OFF_VM   142976   // [48][64]
#define OFF_LM   146048   // [65][64]
#define OFF_CM   150208   // [65][64]
#define OFF_RS   154368   // 1/sigma

__device__ __forceinline__ float wred(float v) {
  #pragma unroll
  for (int m = 32; m >= 1; m >>= 1) v += __shfl_xor(v, m, 64);
  return v;
}

// ===================== K1a: input-only folds (500 blocks) + sigma (block 500) =====================
__global__ __launch_bounds__(256)
void k1a(const float* __restrict__ chemb, const float* __restrict__ aemb,
         const float* __restrict__ zW, const float* __restrict__ zb,
         const float* __restrict__ latW, const float* __restrict__ latb,
         const float* __restrict__ codeW, const float* __restrict__ codeb,
         const float* __restrict__ Wq, const float* __restrict__ Wk,
         const float* __restrict__ Wv, const float* __restrict__ Wo,
         const float* __restrict__ fW, float* __restrict__ ws) {
  __shared__ __align__(16) float sm[13120];    // sigma uses all; fold blocks use first 1024
  const int t = threadIdx.x, b = blockIdx.x;

  if (b == 500) {
    // ---- sigma: G = fW^T fW (fW is [256][64]! K=256 via 4 staged chunks),
    // ----        5 tiled trace-normed squarings, 6 power iters, Rayleigh on G ----
    const int ln = t & 63;
    float* bufA = sm;            // fW^T chunk staging, then ping
    float* G0   = sm + 4352;     // raw G for Rayleigh
    float* bufB = sm + 8704;     // pong
    float* red  = sm + 13056;    // [64] scratch
    const int ty = t >> 4, tx = t & 15;
    const int i0 = ty * 4, j0 = tx * 4;
    float acc[4][4];
    #pragma unroll
    for (int i = 0; i < 4; ++i)
      #pragma unroll
      for (int j = 0; j < 4; ++j) acc[i][j] = 0.f;
    for (int c = 0; c < 4; ++c) {              // K-chunks of 64: G[i][j] = sum_{k<256} fW[k][i] fW[k][j]
      if (c) __syncthreads();                  // prev chunk's reads complete
      for (int e = t; e < 4096; e += 256) {
        int k = e >> 6, i = e & 63;
        bufA[i * 68 + k] = fW[(c * 64 + k) * 64 + i];
      }
      __syncthreads();
      #pragma unroll 4
      for (int k4 = 0; k4 < 16; ++k4) {
        float4 av[4], bv[4];
        #pragma unroll
        for (int i = 0; i < 4; ++i) av[i] = *(const float4*)&bufA[(i0 + i) * 68 + k4 * 4];
        #pragma unroll
        for (int j = 0; j < 4; ++j) bv[j] = *(const float4*)&bufA[(j0 + j) * 68 + k4 * 4];
        #pragma unroll
        for (int i = 0; i < 4; ++i)
          #pragma unroll
          for (int j = 0; j < 4; ++j)
            acc[i][j] += av[i].x * bv[j].x + av[i].y * bv[j].y + av[i].z * bv[j].z + av[i].w * bv[j].w;
      }
    }
    if (ty == tx) red[ty] = acc[0][0] + acc[1][1] + acc[2][2] + acc[3][3];
    __syncthreads();
    {
      float tr = 0.f;
      #pragma unroll
      for (int x = 0; x < 16; ++x) tr += red[x];
      float inv = (tr > 0.f) ? 1.f / tr : 0.f;
      #pragma unroll
      for (int i = 0; i < 4; ++i) {
        *(float4*)&G0[(i0 + i) * 68 + j0]   = make_float4(acc[i][0], acc[i][1], acc[i][2], acc[i][3]);
        *(float4*)&bufB[(i0 + i) * 68 + j0] = make_float4(acc[i][0] * inv, acc[i][1] * inv,
                                                          acc[i][2] * inv, acc[i][3] * inv);
      }
    }
    __syncthreads();
    float* src = bufB;
    float* dst = bufA;
    for (int sq = 0; sq < 5; ++sq) {           // H <- H^2 / tr(H^2); symmetric
      #pragma unroll
      for (int i = 0; i < 4; ++i)
        #pragma unroll
        for (int j = 0; j < 4; ++j) acc[i][j] = 0.f;
      #pragma unroll 4
      for (int k4 = 0; k4 < 16; ++k4) {
        float4 av[4], bv[4];
        #pragma unroll
        for (int i = 0; i < 4; ++i) av[i] = *(const float4*)&src[(i0 + i) * 68 + k4 * 4];
        #pragma unroll
        for (int j = 0; j < 4; ++j) bv[j] = *(const float4*)&src[(j0 + j) * 68 + k4 * 4];
        #pragma unroll
        for (int i = 0; i < 4; ++i)
          #pragma unroll
          for (int j = 0; j < 4; ++j)
            acc[i][j] += av[i].x * bv[j].x + av[i].y * bv[j].y + av[i].z * bv[j].z + av[i].w * bv[j].w;
      }
      if (ty == tx) red[ty] = acc[0][0] + acc[1][1] + acc[2][2] + acc[3][3];
      __syncthreads();
      {
        float tr = 0.f;
        #pragma unroll
        for (int x = 0; x < 16; ++x) tr += red[x];
        float inv = (tr > 0.f) ? 1.f / tr : 0.f;
        #pragma unroll
        for (int i = 0; i < 4; ++i)
          *(float4*)&dst[(i0 + i) * 68 + j0] = make_float4(acc[i][0] * inv, acc[i][1] * inv,
                                                           acc[i][2] * inv, acc[i][3] * inv);
      }
      __syncthreads();
      float* tmp = src; src = dst; dst = tmp;
    }
    // src = G^32 (normalized). Single-wave power iteration + Rayleigh on G0.
    if (t < 64) {
      float4 h[16];
      #pragma unroll
      for (int k4 = 0; k4 < 16; ++k4) h[k4] = *(const float4*)&src[ln * 68 + k4 * 4];
      float rn = 0.f;
      #pragma unroll
      for (int k4 = 0; k4 < 16; ++k4)
        rn += h[k4].x * h[k4].x + h[k4].y * h[k4].y + h[k4].z * h[k4].z + h[k4].w * h[k4].w;
      float bnv = rn; int bj = ln;
      #pragma unroll
      for (int m = 32; m >= 1; m >>= 1) {
        float ov = __shfl_xor(bnv, m, 64);
        int   oj = __shfl_xor(bj, m, 64);
        if (ov > bnv || (ov == bnv && oj < bj)) { bnv = ov; bj = oj; }
      }
      float v = src[bj * 68 + ln];               // column bj (= row bj, symmetric)
      for (int pi = 0; pi < PITERS; ++pi) {
        red[ln] = v;
        float y0 = 0.f, y1 = 0.f, y2 = 0.f, y3 = 0.f;
        #pragma unroll
        for (int k4 = 0; k4 < 16; ++k4) {
          float4 vvv = *(const float4*)&red[k4 * 4];
          y0 = fmaf(h[k4].x, vvv.x, y0);
          y1 = fmaf(h[k4].y, vvv.y, y1);
          y2 = fmaf(h[k4].z, vvv.z, y2);
          y3 = fmaf(h[k4].w, vvv.w, y3);
        }
        float y = (y0 + y1) + (y2 + y3);
        float n2 = wred(y * y);
        v = (n2 > 0.f) ? y * rsqrtf(n2) : 0.f;
      }
      red[ln] = v;
      float y0 = 0.f, y1 = 0.f, y2 = 0.f, y3 = 0.f;
      #pragma unroll
      for (int k4 = 0; k4 < 16; ++k4) {
        float4 gg = *(const float4*)&G0[ln * 68 + k4 * 4];
        float4 vvv = *(const float4*)&red[k4 * 4];
        y0 = fmaf(gg.x, vvv.x, y0);
        y1 = fmaf(gg.y, vvv.y, y1);
        y2 = fmaf(gg.z, vvv.z, y2);
        y3 = fmaf(gg.w, vvv.w, y3);
      }
      float y = (y0 + y1) + (y2 + y3);
      float num = wred(v * y), den = wred(v * v);
      if (ln == 0) {
        float lam = (den > 1e-37f) ? num / den : 0.f;
        lam = fmaxf(lam, 0.f);
        ws[OFF_RS] = 1.f / fmaxf(sqrtf(lam), 1e-8f);
      }
    }
    return;
  }

  // ---- fold unit: 4 output rows per block ----
  float* red = sm;                                    // [4][256]
  const int j = t & 63, ks = t >> 6;
  const float *a0p, *a1p, *a2p, *a3p;
  const float* Bm;
  int bstride = 256, jbase = 0;
  int d0, d1, d2, d3;
  if (b < 340) {                                      // W5: 5 mats x 17 rowgroups x 4 col-chunks
    int u = b / 68, r2 = b - u * 68;
    int rg = r2 >> 2, jc = r2 & 3; jbase = jc * 64;
    const float *Wmat, *bias;
    if (u == 0)      { Wmat = zW;    bias = zb;    Bm = Wq; }
    else if (u == 1) { Wmat = latW;  bias = latb;  Bm = Wk; }
    else if (u == 2) { Wmat = codeW; bias = codeb; Bm = Wk; }
    else if (u == 3) { Wmat = latW;  bias = latb;  Bm = Wv; }
    else             { Wmat = codeW; bias = codeb; Bm = Wv; }
    int r0 = rg * 4;
    int rr1 = r0 + 1, rr2 = r0 + 2, rr3 = r0 + 3;
    a0p = (r0 < 64) ? (Wmat + r0 * 256) : bias;
    a1p = (rr1 < 64) ? (Wmat + rr1 * 256) : bias;
    a2p = (rr2 < 64) ? (Wmat + rr2 * 256) : bias;
    a3p = (rr3 < 64) ? (Wmat + rr3 * 256) : bias;
    d0 = u * 16640 + r0 * 256 + jbase;
    d1 = (rr1 <= 64) ? (u * 16640 + rr1 * 256 + jbase) : -1;
    d2 = (rr2 <= 64) ? (u * 16640 + rr2 * 256 + jbase) : -1;
    d3 = (rr3 <= 64) ? (u * 16640 + rr3 * 256 + jbase) : -1;
  } else if (b < 436) {                               // KE/VE
    int b2 = b - 340; int isV = (b2 >= 48); int rr = b2 - (isV ? 48 : 0);
    int rg = rr >> 2, jc = rr & 3; jbase = jc * 64;
    Bm = isV ? Wv : Wk;
    int base = isV ? OFF_VE : OFF_KE;
    int s0 = rg * 4;
    a0p = (s0 + 0 < 16) ? (aemb + (s0 + 0) * 256) : (chemb + (s0 + 0 - 16) * 256);
    a1p = (s0 + 1 < 16) ? (aemb + (s0 + 1) * 256) : (chemb + (s0 + 1 - 16) * 256);
    a2p = (s0 + 2 < 16) ? (aemb + (s0 + 2) * 256) : (chemb + (s0 + 2 - 16) * 256);
    a3p = (s0 + 3 < 16) ? (aemb + (s0 + 3) * 256) : (chemb + (s0 + 3 - 16) * 256);
    d0 = base + (s0 + 0) * 256 + jbase;
    d1 = base + (s0 + 1) * 256 + jbase;
    d2 = base + (s0 + 2) * 256 + jbase;
    d3 = base + (s0 + 3) * 256 + jbase;
  } else {                                            // M = Wo @ fW
    int i0 = (b - 436) * 4;
    Bm = fW; bstride = 64;
    a0p = Wo + (i0 + 0) * 256; a1p = Wo + (i0 + 1) * 256;
    a2p = Wo + (i0 + 2) * 256; a3p = Wo + (i0 + 3) * 256;
    d0 = OFF_M + (i0 + 0) * 64; d1 = OFF_M + (i0 + 1) * 64;
    d2 = OFF_M + (i0 + 2) * 64; d3 = OFF_M + (i0 + 3) * 64;
  }
  float acc0 = 0.f, acc1 = 0.f, acc2 = 0.f, acc3 = 0.f;
  const float* bp = Bm + (ks * 64) * bstride + jbase + j;
  const float* a0 = a0p + ks * 64;
  const float* a1 = a1p + ks * 64;
  const float* a2 = a2p + ks * 64;
  const float* a3 = a3p + ks * 64;
  #pragma unroll 4
  for (int k4 = 0; k4 < 16; ++k4) {
    float b0 = bp[(k4 * 4 + 0) * bstride];
    float b1 = bp[(k4 * 4 + 1) * bstride];
    float b2 = bp[(k4 * 4 + 2) * bstride];
    float b3 = bp[(k4 * 4 + 3) * bstride];
    float4 x0 = *(const float4*)(a0 + k4 * 4);
    float4 x1 = *(const float4*)(a1 + k4 * 4);
    float4 x2 = *(const float4*)(a2 + k4 * 4);
    float4 x3 = *(const float4*)(a3 + k4 * 4);
    acc0 += x0.x * b0 + x0.y * b1 + x0.z * b2 + x0.w * b3;
    acc1 += x1.x * b0 + x1.y * b1 + x1.z * b2 + x1.w * b3;
    acc2 += x2.x * b0 + x2.y * b1 + x2.z * b2 + x2.w * b3;
    acc3 += x3.x * b0 + x3.y * b1 + x3.z * b2 + x3.w * b3;
  }
  red[0 * 256 + t] = acc0;
  red[1 * 256 + t] = acc1;
  red[2 * 256 + t] = acc2;
  red[3 * 256 + t] = acc3;
  __syncthreads();
  if (t < 64) {
    if (d0 >= 0) ws[d0 + t] = (red[t] + red[64 + t]) + (red[128 + t] + red[192 + t]);
    if (d1 >= 0) ws[d1 + t] = (red[256 + t] + red[320 + t]) + (red[384 + t] + red[448 + t]);
    if (d2 >= 0) ws[d2 + t] = (red[512 + t] + red[576 + t]) + (red[640 + t] + red[704 + t]);
    if (d3 >= 0) ws[d3 + t] = (red[768 + t] + red[832 + t]) + (red[896 + t] + red[960 + t]);
  }
}

// ===================== K1b: pairwise folds, 375 blocks =====================
__global__ __launch_bounds__(256)
void k1b(const float* __restrict__ latb, const float* __restrict__ codeb,
         const float* __restrict__ aanc, const float* __restrict__ chanc,
         float* __restrict__ ws) {
  __shared__ float red[256];
  const int t = threadIdx.x, q = blockIdx.x;

  if (q == 374) {                 // ANCT [64 d][48 s] + ANCN
    for (int e = t; e < 3072; e += 256) {
      int d = e / 48, s = e - d * 48;
      const float* a = (s < 16) ? (aanc + s * 64) : (chanc + (s - 16) * 64);
      ws[OFF_ANCT + e] = a[d];
    }
    if (t < 64) {
      float n = 0.f;
      if (t < 48) {
        const float* a = (t < 16) ? (aanc + t * 64) : (chanc + (t - 16) * 64);
        #pragma unroll 4
        for (int d = 0; d < 64; ++d) n += a[d] * a[d];
      }
      ws[OFF_ANCN + t] = n;
    }
    return;
  }
  if (q == 373) {                 // PLc[r] = XQ[r]·KL[64] ; PCc[r] = XQ[r]·KC[64]
    if (t < 65) {
      const float* ap = ws + OFF_XQ + t * 256;
      const float* bp = ws + OFF_KL + 64 * 256;
      float acc = 0.f;
      #pragma unroll 4
      for (int e = 0; e < 256; ++e) acc += ap[e] * bp[e];
      ws[OFF_PLc + t] = acc;
    } else if (t >= 128 && t < 193) {
      int r = t - 128;
      const float* ap = ws + OFF_XQ + r * 256;
      const float* bp = ws + OFF_KC + 64 * 256;
      float acc = 0.f;
      #pragma unroll 4
      for (int e = 0; e < 256; ++e) acc += ap[e] * bp[e];
      ws[OFF_PCc + r] = acc;
    }
    return;
  }

  const int j = t & 63, ks = t >> 6;
  const float* ap; const float* bp;
  int bstride, dstBase, nout = 64;
  if (q < 325) {
    int g = q / 65, r = q - g * 65;
    const float* A = ws + ((g < 3) ? OFF_XQ : (g == 3 ? OFF_VL : OFF_VC)) + r * 256;
    if (g == 0)      { bp = ws + OFF_KL + j * 256 + ks * 64; bstride = 1; dstBase = OFF_PLm + r * 64; }
    else if (g == 1) { bp = ws + OFF_KC + j * 256 + ks * 64; bstride = 1; dstBase = OFF_PCm + r * 64; }
    else if (g == 2) { int jj = (j < 48) ? j : 47;
                       bp = ws + OFF_KE + jj * 256 + ks * 64; bstride = 1; dstBase = OFF_CK2 + r * 48; nout = 48; }
    else if (g == 3) { bp = ws + OFF_M + (ks * 64) * 64 + j; bstride = 64; dstBase = OFF_LM + r * 64; }
    else             { bp = ws + OFF_M + (ks * 64) * 64 + j; bstride = 64; dstBase = OFF_CM + r * 64; }
    ap = A + ks * 64;
  } else {                        // VM[s] = VE[s]@M
    int s = q - 325;
    ap = ws + OFF_VE + s * 256 + ks * 64;
    bp = ws + OFF_M + (ks * 64) * 64 + j; bstride = 64;
    dstBase = OFF_VM + s * 64;
  }
  float a0 = 0.f, a1 = 0.f, a2 = 0.f, a3 = 0.f;
  #pragma unroll 4
  for (int k = 0; k < 64; k += 4) {
    a0 += ap[k + 0] * bp[(k + 0) * bstride];
    a1 += ap[k + 1] * bp[(k + 1) * bstride];
    a2 += ap[k + 2] * bp[(k + 2) * bstride];
    a3 += ap[k + 3] * bp[(k + 3) * bstride];
  }
  red[t] = (a0 + a1) + (a2 + a3);
  __syncthreads();
  if (t < nout) ws[dstBase + t] = red[t] + red[64 + t] + red[128 + t] + red[192 + t];
}

// ===================== K2: wave-per-2-batches main path; writes out directly =====================
__global__ __launch_bounds__(256)
void k2_main(const float* __restrict__ z, const float* __restrict__ rw,
             const float* __restrict__ az, const float* __restrict__ arw,
             const float* __restrict__ acz, const float* __restrict__ ctrl,
             const float* __restrict__ ecov, const float* __restrict__ fb,
             const float* __restrict__ ws, float* __restrict__ out) {
  const int t = threadIdx.x;
  const int wv = t >> 6, ln = t & 63;

  const int bb = blockIdx.x * 8 + wv * 2;
  float z0 = z[bb * 64 + ln],        z1 = z[(bb + 1) * 64 + ln];
  float a0 = az[bb * 64 + ln],       a1 = az[(bb + 1) * 64 + ln];
  float c0 = acz[bb * 64 + ln],      c1 = acz[(bb + 1) * 64 + ln];
  float cc0 = ctrl[bb * 64 + ln],    cc1 = ctrl[(bb + 1) * 64 + ln];
  float ee0 = ecov[bb * 64 + ln],    ee1 = ecov[(bb + 1) * 64 + ln];
  float fbv = fb[ln];
  const float rs = ws[OFF_RS];
  float fold0 = 1.f, fold1 = 1.f;
  if (ln < 16)      { fold0 = arw[bb * 16 + ln];        fold1 = arw[(bb + 1) * 16 + ln]; }
  else if (ln < 48) { fold0 = rw[bb * 32 + (ln - 16)];  fold1 = rw[(bb + 1) * 32 + (ln - 16)]; }

  float dL0 = wred((z0 - a0) * (z0 - a0));
  float dL1 = wred((z1 - a1) * (z1 - a1));
  float dC0 = wred((z0 - c0) * (z0 - c0));
  float dC1 = wred((z1 - c1) * (z1 - c1));
  float zn0 = wred(z0 * z0);
  float zn1 = wred(z1 * z1);

  const float* plm = ws + OFF_PLm + ln;
  const float* pcm = ws + OFF_PCm + ln;
  float uL0 = plm[64 * 64], uL1 = uL0;
  float uC0 = pcm[64 * 64], uC1 = uC0;
  #pragma unroll 8
  for (int k = 0; k < 64; ++k) {
    float pm = plm[k * 64], pc = pcm[k * 64];
    float zk0 = __shfl(z0, k, 64), zk1 = __shfl(z1, k, 64);
    uL0 = fmaf(zk0, pm, uL0); uL1 = fmaf(zk1, pm, uL1);
    uC0 = fmaf(zk0, pc, uC0); uC1 = fmaf(zk1, pc, uC1);
  }
  float plc = ws[OFF_PLc + ln], pcc = ws[OFF_PCc + ln];
  float plcc = ws[OFF_PLc + 64], pccc = ws[OFF_PCc + 64];
  float sL0 = wred(uL0 * a0 + z0 * plc) + plcc;
  float sL1 = wred(uL1 * a1 + z1 * plc) + plcc;
  float sC0 = wred(uC0 * c0 + z0 * pcc) + pccc;
  float sC1 = wred(uC1 * c1 + z1 * pcc) + pccc;
  float scl0 = sL0 * 0.0625f - dL0, scl1 = sL1 * 0.0625f - dL1;
  float scc0 = sC0 * 0.0625f - dC0, scc1 = sC1 * 0.0625f - dC1;

  const float* ck = ws + OFF_CK2 + ln;
  const float* an = ws + OFF_ANCT + ln;
  float ca0 = ck[64 * 48], ca1 = ca0;
  float za0 = 0.f, za1 = 0.f;
  #pragma unroll 8
  for (int k = 0; k < 64; ++k) {
    float cv = ck[k * 48], av = an[k * 48];
    float zk0 = __shfl(z0, k, 64), zk1 = __shfl(z1, k, 64);
    ca0 = fmaf(zk0, cv, ca0); ca1 = fmaf(zk1, cv, ca1);
    za0 = fmaf(zk0, av, za0); za1 = fmaf(zk1, av, za1);
  }
  float ancn = ws[OFF_ANCN + ln];
  float sc0 = fold0 * ca0 * 0.0625f - (zn0 - 2.f * za0 + ancn);
  float sc1 = fold1 * ca1 * 0.0625f - (zn1 - 2.f * za1 + ancn);
  if (ln == 48) { sc0 = scl0; sc1 = scl1; }
  if (ln == 49) { sc0 = scc0; sc1 = scc1; }
  if (ln > 49)  { sc0 = -1e30f; sc1 = -1e30f; }

  float mx0 = sc0, mx1 = sc1;
  #pragma unroll
  for (int m = 32; m >= 1; m >>= 1) {
    mx0 = fmaxf(mx0, __shfl_xor(mx0, m, 64));
    mx1 = fmaxf(mx1, __shfl_xor(mx1, m, 64));
  }
  float ev0 = (ln < 50) ? __expf(sc0 - mx0) : 0.f;
  float ev1 = (ln < 50) ? __expf(sc1 - mx1) : 0.f;
  float sum0 = wred(ev0), sum1 = wred(ev1);
  float w0 = ev0 * (1.f / sum0) * fold0;
  float w1 = ev1 * (1.f / sum1) * fold1;

  float g0 = 0.f, g1 = 0.f;
  const float* vm = ws + OFF_VM + ln;
  #pragma unroll 8
  for (int s = 0; s < 48; ++s) {
    float vvv = vm[s * 64];
    float s0 = __shfl(w0, s, 64), s1 = __shfl(w1, s, 64);
    g0 = fmaf(s0, vvv, g0); g1 = fmaf(s1, vvv, g1);
  }
  const float* lm = ws + OFF_LM + ln;
  const float* cm = ws + OFF_CM + ln;
  float l0 = lm[64 * 64], l1 = l0;
  float m0 = cm[64 * 64], m1 = m0;
  #pragma unroll 8
  for (int k = 0; k < 64; ++k) {
    float lv = lm[k * 64], cv = cm[k * 64];
    float ak0 = __shfl(a0, k, 64), ak1 = __shfl(a1, k, 64);
    float qk0 = __shfl(c0, k, 64), qk1 = __shfl(c1, k, 64);
    l0 = fmaf(ak0, lv, l0); l1 = fmaf(ak1, lv, l1);
    m0 = fmaf(qk0, cv, m0); m1 = fmaf(qk1, cv, m1);
  }
  float w48_0 = __shfl(w0, 48, 64), w49_0 = __shfl(w0, 49, 64);
  float w48_1 = __shfl(w1, 48, 64), w49_1 = __shfl(w1, 49, 64);
  g0 += w48_0 * l0 + w49_0 * m0;
  g1 += w48_1 * l1 + w49_1 * m1;

  #pragma unroll
  for (int s = 0; s < 2; ++s) {
    float g  = (s == 0) ? g0 : g1;
    float cc = (s == 0) ? cc0 : cc1;
    float ee = (s == 0) ? ee0 : ee1;
    int bbs  = bb + s;
    float gc = wred(g * cc);
    float ge = wred(g * ee);
    float ec = wred(ee * cc);
    float en = wred(ee * ee);
    float fc = wred(fbv * cc);
    float fe = wred(fbv * ee);
    if (ln == 0) {
      float A, Bv;
      if (en > 1e-8f) { float r = ec / en; A = gc - ge * r; Bv = fc - fe * r; }
      else { A = gc; Bv = fc; }
      out[bbs] = A * rs + Bv;
    }
  }
}

extern "C" void kernel_launch(void* const* d_in, const int* in_sizes, int n_in,
                              void* d_out, int out_size, void* d_ws, size_t ws_size,
                              hipStream_t stream) {
  const float* z     = (const float*)d_in[0];
  const float* rw    = (const float*)d_in[1];
  const float* az    = (const float*)d_in[2];
  const float* arw   = (const float*)d_in[3];
  const float* acz   = (const float*)d_in[4];
  const float* ctrl  = (const float*)d_in[5];
  const float* ecov  = (const float*)d_in[6];
  const float* chemb = (const float*)d_in[7];
  const float* chanc = (const float*)d_in[8];
  const float* aemb  = (const float*)d_in[9];
  const float* aanc  = (const float*)d_in[10];
  const float* zW    = (const float*)d_in[11];
  const float* zb    = (const float*)d_in[12];
  const float* latW  = (const float*)d_in[13];
  const float* latb  = (const float*)d_in[14];
  const float* codeW = (const float*)d_in[15];
  const float* codeb = (const float*)d_in[16];
  const float* Wq    = (const float*)d_in[17];
  const float* Wk    = (const float*)d_in[18];
  const float* Wv    = (const float*)d_in[19];
  const float* Wo    = (const float*)d_in[20];
  const float* fW    = (const float*)d_in[21];
  const float* fb    = (const float*)d_in[22];
  float* ws  = (float*)d_ws;
  float* out = (float*)d_out;

  k1a<<<501, 256, 0, stream>>>(chemb, aemb, zW, zb, latW, latb, codeW, codeb,
                               Wq, Wk, Wv, Wo, fW, ws);
  k1b<<<375, 256, 0, stream>>>(latb, codeb, aanc, chanc, ws);
  k2_main<<<512, 256, 0, stream>>>(z, rw, az, arw, acz, ctrl, ecov, fb, ws, out);
}

// Round 12
// 155.030 us; speedup vs baseline: 1.1951x; 1.1951x over previous
//
#include <hip/hip_runtime.h>

// B=4096, D=64, DM=256, K=32, KA=16, S=50
#define PITERS 24

// ---- workspace layout (float offsets) ----
// stage-1 (dead after k1b):
#define OFF_XQ   0        // [65][256]  Zf@Wq
#define OFF_KL   16640    // [65][256]  Lf@Wk
#define OFF_KC   33280    // [65][256]  Cf@Wk
#define OFF_VL   49920    // [65][256]  Lf@Wv
#define OFF_VC   66560    // [65][256]  Cf@Wv
#define OFF_KE   83200    // [48][256]  EMB@Wk
#define OFF_VE   95488    // [48][256]  EMB@Wv
#define OFF_M    107776   // [256][64]  Wo@fW
#define OFF_G    124160   // [64][64]   fW^T fW
// stage-2 (k2 inputs):
#define OFF_PLm  128256   // [65][64]
#define OFF_PLc  132416   // [72]
#define OFF_PCm  132488   // [65][64]
#define OFF_PCc  136648   // [72]
#define OFF_CK2  136720   // [65][48]
#define OFF_ANCT 139840   // [64][48]
#define OFF_ANCN 142912   // [64]
#define OFF_VM   142976   // [48][64]
#define OFF_LM   146048   // [65][64]
#define OFF_CM   150208   // [65][64]
#define OFF_RS   154368   // 1/sigma

__device__ __forceinline__ float wred(float v) {
  #pragma unroll
  for (int m = 32; m >= 1; m >>= 1) v += __shfl_xor(v, m, 64);
  return v;
}

// ===================== K1a (R7-verified): 500 four-row folds + 16 G-tile blocks =====================
__global__ __launch_bounds__(256)
void k1a(const float* __restrict__ chemb, const float* __restrict__ aemb,
         const float* __restrict__ zW, const float* __restrict__ zb,
         const float* __restrict__ latW, const float* __restrict__ latb,
         const float* __restrict__ codeW, const float* __restrict__ codeb,
         const float* __restrict__ Wq, const float* __restrict__ Wk,
         const float* __restrict__ Wv, const float* __restrict__ Wo,
         const float* __restrict__ fW, float* __restrict__ ws) {
  __shared__ __align__(16) float red[1024];
  const int t = threadIdx.x, b = blockIdx.x;
  const int j = t & 63, ks = t >> 6;

  const float *a0p, *a1p, *a2p, *a3p;
  const float* Bm;
  int bstride = 256, jbase = 0;
  int d0, d1, d2, d3;
  bool gpath = false;

  if (b < 340) {                        // W5: rows 0..64 (row 64 = bias)
    int u = b / 68, r2 = b - u * 68;
    int rg = r2 >> 2, jc = r2 & 3; jbase = jc * 64;
    const float *Wmat, *bias;
    if (u == 0)      { Wmat = zW;    bias = zb;    Bm = Wq; }
    else if (u == 1) { Wmat = latW;  bias = latb;  Bm = Wk; }
    else if (u == 2) { Wmat = codeW; bias = codeb; Bm = Wk; }
    else if (u == 3) { Wmat = latW;  bias = latb;  Bm = Wv; }
    else             { Wmat = codeW; bias = codeb; Bm = Wv; }
    int r0 = rg * 4;
    int rr1 = r0 + 1, rr2 = r0 + 2, rr3 = r0 + 3;
    a0p = (r0 < 64) ? (Wmat + r0 * 256) : bias;
    a1p = (rr1 < 64) ? (Wmat + rr1 * 256) : bias;
    a2p = (rr2 < 64) ? (Wmat + rr2 * 256) : bias;
    a3p = (rr3 < 64) ? (Wmat + rr3 * 256) : bias;
    d0 = u * 16640 + r0 * 256 + jbase;
    d1 = (rr1 <= 64) ? (u * 16640 + rr1 * 256 + jbase) : -1;
    d2 = (rr2 <= 64) ? (u * 16640 + rr2 * 256 + jbase) : -1;
    d3 = (rr3 <= 64) ? (u * 16640 + rr3 * 256 + jbase) : -1;
  } else if (b < 436) {                 // KE/VE: 48 rows each
    int b2 = b - 340; int isV = (b2 >= 48); int rr = b2 - (isV ? 48 : 0);
    int rg = rr >> 2, jc = rr & 3; jbase = jc * 64;
    Bm = isV ? Wv : Wk;
    int base = isV ? OFF_VE : OFF_KE;
    int s0 = rg * 4;
    a0p = (s0 + 0 < 16) ? (aemb + (s0 + 0) * 256) : (chemb + (s0 + 0 - 16) * 256);
    a1p = (s0 + 1 < 16) ? (aemb + (s0 + 1) * 256) : (chemb + (s0 + 1 - 16) * 256);
    a2p = (s0 + 2 < 16) ? (aemb + (s0 + 2) * 256) : (chemb + (s0 + 2 - 16) * 256);
    a3p = (s0 + 3 < 16) ? (aemb + (s0 + 3) * 256) : (chemb + (s0 + 3 - 16) * 256);
    d0 = base + (s0 + 0) * 256 + jbase;
    d1 = base + (s0 + 1) * 256 + jbase;
    d2 = base + (s0 + 2) * 256 + jbase;
    d3 = base + (s0 + 3) * 256 + jbase;
  } else if (b < 500) {                 // M = Wo @ fW
    int i0 = (b - 436) * 4;
    Bm = fW; bstride = 64;
    a0p = Wo + (i0 + 0) * 256; a1p = Wo + (i0 + 1) * 256;
    a2p = Wo + (i0 + 2) * 256; a3p = Wo + (i0 + 3) * 256;
    d0 = OFF_M + (i0 + 0) * 64; d1 = OFF_M + (i0 + 1) * 64;
    d2 = OFF_M + (i0 + 2) * 64; d3 = OFF_M + (i0 + 3) * 64;
  } else {                              // G = fW^T fW (A = columns of fW, K=256 via 4 ks groups)
    gpath = true;
    int i0 = (b - 500) * 4;
    Bm = fW; bstride = 64;
    a0p = fW + i0 + 0; a1p = fW + i0 + 1; a2p = fW + i0 + 2; a3p = fW + i0 + 3;
    d0 = OFF_G + (i0 + 0) * 64; d1 = OFF_G + (i0 + 1) * 64;
    d2 = OFF_G + (i0 + 2) * 64; d3 = OFF_G + (i0 + 3) * 64;
  }

  float acc0 = 0.f, acc1 = 0.f, acc2 = 0.f, acc3 = 0.f;
  const float* bp = Bm + (ks * 64) * bstride + jbase + j;
  if (!gpath) {
    const float* a0 = a0p + ks * 64;
    const float* a1 = a1p + ks * 64;
    const float* a2 = a2p + ks * 64;
    const float* a3 = a3p + ks * 64;
    #pragma unroll 4
    for (int k4 = 0; k4 < 16; ++k4) {
      float b0 = bp[(k4 * 4 + 0) * bstride];
      float b1 = bp[(k4 * 4 + 1) * bstride];
      float b2 = bp[(k4 * 4 + 2) * bstride];
      float b3 = bp[(k4 * 4 + 3) * bstride];
      float4 x0 = *(const float4*)(a0 + k4 * 4);
      float4 x1 = *(const float4*)(a1 + k4 * 4);
      float4 x2 = *(const float4*)(a2 + k4 * 4);
      float4 x3 = *(const float4*)(a3 + k4 * 4);
      acc0 += x0.x * b0 + x0.y * b1 + x0.z * b2 + x0.w * b3;
      acc1 += x1.x * b0 + x1.y * b1 + x1.z * b2 + x1.w * b3;
      acc2 += x2.x * b0 + x2.y * b1 + x2.z * b2 + x2.w * b3;
      acc3 += x3.x * b0 + x3.y * b1 + x3.z * b2 + x3.w * b3;
    }
  } else {
    const float* a0 = a0p + (ks * 64) * 64;
    const float* a1 = a1p + (ks * 64) * 64;
    const float* a2 = a2p + (ks * 64) * 64;
    const float* a3 = a3p + (ks * 64) * 64;
    #pragma unroll 4
    for (int k = 0; k < 64; ++k) {
      float bv = bp[k * bstride];
      acc0 += a0[k * 64] * bv;
      acc1 += a1[k * 64] * bv;
      acc2 += a2[k * 64] * bv;
      acc3 += a3[k * 64] * bv;
    }
  }
  red[0 * 256 + t] = acc0;
  red[1 * 256 + t] = acc1;
  red[2 * 256 + t] = acc2;
  red[3 * 256 + t] = acc3;
  __syncthreads();
  if (t < 64) {
    if (d0 >= 0) ws[d0 + t] = (red[t] + red[64 + t]) + (red[128 + t] + red[192 + t]);
    if (d1 >= 0) ws[d1 + t] = (red[256 + t] + red[320 + t]) + (red[384 + t] + red[448 + t]);
    if (d2 >= 0) ws[d2 + t] = (red[512 + t] + red[576 + t]) + (red[640 + t] + red[704 + t]);
    if (d3 >= 0) ws[d3 + t] = (red[768 + t] + red[832 + t]) + (red[896 + t] + red[960 + t]);
  }
}

// ===================== K1b: 375 pairwise folds + sigma (block 375) =====================
__global__ __launch_bounds__(256)
void k1b(const float* __restrict__ latb, const float* __restrict__ codeb,
         const float* __restrict__ aanc, const float* __restrict__ chanc,
         float* __restrict__ ws) {
  __shared__ __align__(16) float sm[13120];   // sigma uses all; fold blocks use first 256
  const int t = threadIdx.x, q = blockIdx.x;

  if (q == 375) {
    // ---- sigma: G from ws (k1a-verified), 2 tiled trace-normed squarings -> G^4,
    // ----        24 single-wave power iters (LDS-broadcast, R10-verified), Rayleigh on G ----
    const int ln = t & 63;
    float* bufA = sm;            // ping (G/tr, then H)
    float* G0   = sm + 4352;     // raw G for Rayleigh
    float* bufB = sm + 8704;     // pong
    float* red  = sm + 13056;    // [64] scratch
    {
      float tv = (t < 64) ? ws[OFF_G + t * 65] : 0.f;   // diag
      tv = wred(tv);
      if (t == 0) red[0] = (tv > 0.f) ? 1.f / tv : 0.f;
    }
    __syncthreads();
    {
      float inv0 = red[0];
      for (int e = t; e < 4096; e += 256) {
        int i = e >> 6, jj = e & 63;
        float g = ws[OFF_G + e];
        G0[i * 68 + jj]   = g;
        bufA[i * 68 + jj] = g * inv0;
      }
    }
    __syncthreads();
    const int ty = t >> 4, tx = t & 15;
    const int i0 = ty * 4, j0 = tx * 4;
    float* src = bufA;
    float* dst = bufB;
    for (int sq = 0; sq < 2; ++sq) {           // H <- H^2 / tr(H^2); symmetric
      float acc[4][4];
      #pragma unroll
      for (int i = 0; i < 4; ++i)
        #pragma unroll
        for (int j = 0; j < 4; ++j) acc[i][j] = 0.f;
      #pragma unroll 4
      for (int k4 = 0; k4 < 16; ++k4) {
        float4 av[4], bv[4];
        #pragma unroll
        for (int i = 0; i < 4; ++i) av[i] = *(const float4*)&src[(i0 + i) * 68 + k4 * 4];
        #pragma unroll
        for (int j = 0; j < 4; ++j) bv[j] = *(const float4*)&src[(j0 + j) * 68 + k4 * 4];
        #pragma unroll
        for (int i = 0; i < 4; ++i)
          #pragma unroll
          for (int j = 0; j < 4; ++j)
            acc[i][j] += av[i].x * bv[j].x + av[i].y * bv[j].y + av[i].z * bv[j].z + av[i].w * bv[j].w;
      }
      if (ty == tx) red[ty] = acc[0][0] + acc[1][1] + acc[2][2] + acc[3][3];
      __syncthreads();
      {
        float tr = 0.f;
        #pragma unroll
        for (int x = 0; x < 16; ++x) tr += red[x];
        float inv = (tr > 0.f) ? 1.f / tr : 0.f;
        #pragma unroll
        for (int i = 0; i < 4; ++i)
          *(float4*)&dst[(i0 + i) * 68 + j0] = make_float4(acc[i][0] * inv, acc[i][1] * inv,
                                                           acc[i][2] * inv, acc[i][3] * inv);
      }
      __syncthreads();
      float* tmp = src; src = dst; dst = tmp;
    }
    // src = G^4 (normalized), back in bufA. Single-wave power iteration + Rayleigh on G0.
    if (t < 64) {
      float4 h[16];
      #pragma unroll
      for (int k4 = 0; k4 < 16; ++k4) h[k4] = *(const float4*)&src[ln * 68 + k4 * 4];
      float rn = 0.f;
      #pragma unroll
      for (int k4 = 0; k4 < 16; ++k4)
        rn += h[k4].x * h[k4].x + h[k4].y * h[k4].y + h[k4].z * h[k4].z + h[k4].w * h[k4].w;
      float bnv = rn; int bj = ln;
      #pragma unroll
      for (int m = 32; m >= 1; m >>= 1) {
        float ov = __shfl_xor(bnv, m, 64);
        int   oj = __shfl_xor(bj, m, 64);
        if (ov > bnv || (ov == bnv && oj < bj)) { bnv = ov; bj = oj; }
      }
      float v = src[bj * 68 + ln];               // column bj (= row bj, symmetric)
      for (int pi = 0; pi < PITERS; ++pi) {
        red[ln] = v;
        float y0 = 0.f, y1 = 0.f, y2 = 0.f, y3 = 0.f;
        #pragma unroll
        for (int k4 = 0; k4 < 16; ++k4) {
          float4 vvv = *(const float4*)&red[k4 * 4];
          y0 = fmaf(h[k4].x, vvv.x, y0);
          y1 = fmaf(h[k4].y, vvv.y, y1);
          y2 = fmaf(h[k4].z, vvv.z, y2);
          y3 = fmaf(h[k4].w, vvv.w, y3);
        }
        float y = (y0 + y1) + (y2 + y3);
        float n2 = wred(y * y);
        v = (n2 > 0.f) ? y * rsqrtf(n2) : 0.f;
      }
      red[ln] = v;
      float y0 = 0.f, y1 = 0.f, y2 = 0.f, y3 = 0.f;
      #pragma unroll
      for (int k4 = 0; k4 < 16; ++k4) {
        float4 gg = *(const float4*)&G0[ln * 68 + k4 * 4];
        float4 vvv = *(const float4*)&red[k4 * 4];
        y0 = fmaf(gg.x, vvv.x, y0);
        y1 = fmaf(gg.y, vvv.y, y1);
        y2 = fmaf(gg.z, vvv.z, y2);
        y3 = fmaf(gg.w, vvv.w, y3);
      }
      float y = (y0 + y1) + (y2 + y3);
      float num = wred(v * y), den = wred(v * v);
      if (ln == 0) {
        float lam = (den > 1e-37f) ? num / den : 0.f;
        lam = fmaxf(lam, 0.f);
        ws[OFF_RS] = 1.f / fmaxf(sqrtf(lam), 1e-8f);
      }
    }
    return;
  }

  // ---- fold units (R10-verified) ----
  float* red = sm;
  if (q == 374) {                 // ANCT [64 d][48 s] + ANCN
    for (int e = t; e < 3072; e += 256) {
      int d = e / 48, s = e - d * 48;
      const float* a = (s < 16) ? (aanc + s * 64) : (chanc + (s - 16) * 64);
      ws[OFF_ANCT + e] = a[d];
    }
    if (t < 64) {
      float n = 0.f;
      if (t < 48) {
        const float* a = (t < 16) ? (aanc + t * 64) : (chanc + (t - 16) * 64);
        #pragma unroll 4
        for (int d = 0; d < 64; ++d) n += a[d] * a[d];
      }
      ws[OFF_ANCN + t] = n;
    }
    return;
  }
  if (q == 373) {                 // PLc[r] = XQ[r]·KL[64] ; PCc[r] = XQ[r]·KC[64]
    if (t < 65) {
      const float* ap = ws + OFF_XQ + t * 256;
      const float* bp = ws + OFF_KL + 64 * 256;
      float acc = 0.f;
      #pragma unroll 4
      for (int e = 0; e < 256; ++e) acc += ap[e] * bp[e];
      ws[OFF_PLc + t] = acc;
    } else if (t >= 128 && t < 193) {
      int r = t - 128;
      const float* ap = ws + OFF_XQ + r * 256;
      const float* bp = ws + OFF_KC + 64 * 256;
      float acc = 0.f;
      #pragma unroll 4
      for (int e = 0; e < 256; ++e) acc += ap[e] * bp[e];
      ws[OFF_PCc + r] = acc;
    }
    return;
  }

  const int j = t & 63, ks = t >> 6;
  const float* ap; const float* bp;
  int bstride, dstBase, nout = 64;
  if (q < 325) {
    int g = q / 65, r = q - g * 65;
    const float* A = ws + ((g < 3) ? OFF_XQ : (g == 3 ? OFF_VL : OFF_VC)) + r * 256;
    if (g == 0)      { bp = ws + OFF_KL + j * 256 + ks * 64; bstride = 1; dstBase = OFF_PLm + r * 64; }
    else if (g == 1) { bp = ws + OFF_KC + j * 256 + ks * 64; bstride = 1; dstBase = OFF_PCm + r * 64; }
    else if (g == 2) { int jj = (j < 48) ? j : 47;
                       bp = ws + OFF_KE + jj * 256 + ks * 64; bstride = 1; dstBase = OFF_CK2 + r * 48; nout = 48; }
    else if (g == 3) { bp = ws + OFF_M + (ks * 64) * 64 + j; bstride = 64; dstBase = OFF_LM + r * 64; }
    else             { bp = ws + OFF_M + (ks * 64) * 64 + j; bstride = 64; dstBase = OFF_CM + r * 64; }
    ap = A + ks * 64;
  } else {                        // VM[s] = VE[s]@M
    int s = q - 325;
    ap = ws + OFF_VE + s * 256 + ks * 64;
    bp = ws + OFF_M + (ks * 64) * 64 + j; bstride = 64;
    dstBase = OFF_VM + s * 64;
  }
  float a0 = 0.f, a1 = 0.f, a2 = 0.f, a3 = 0.f;
  #pragma unroll 4
  for (int k = 0; k < 64; k += 4) {
    a0 += ap[k + 0] * bp[(k + 0) * bstride];
    a1 += ap[k + 1] * bp[(k + 1) * bstride];
    a2 += ap[k + 2] * bp[(k + 2) * bstride];
    a3 += ap[k + 3] * bp[(k + 3) * bstride];
  }
  red[t] = (a0 + a1) + (a2 + a3);
  __syncthreads();
  if (t < nout) ws[dstBase + t] = red[t] + red[64 + t] + red[128 + t] + red[192 + t];
}

// ===================== K2 (R10-verified): wave-per-2-batches main path; writes out =====================
__global__ __launch_bounds__(256)
void k2_main(const float* __restrict__ z, const float* __restrict__ rw,
             const float* __restrict__ az, const float* __restrict__ arw,
             const float* __restrict__ acz, const float* __restrict__ ctrl,
             const float* __restrict__ ecov, const float* __restrict__ fb,
             const float* __restrict__ ws, float* __restrict__ out) {
  const int t = threadIdx.x;
  const int wv = t >> 6, ln = t & 63;

  const int bb = blockIdx.x * 8 + wv * 2;
  float z0 = z[bb * 64 + ln],        z1 = z[(bb + 1) * 64 + ln];
  float a0 = az[bb * 64 + ln],       a1 = az[(bb + 1) * 64 + ln];
  float c0 = acz[bb * 64 + ln],      c1 = acz[(bb + 1) * 64 + ln];
  float cc0 = ctrl[bb * 64 + ln],    cc1 = ctrl[(bb + 1) * 64 + ln];
  float ee0 = ecov[bb * 64 + ln],    ee1 = ecov[(bb + 1) * 64 + ln];
  float fbv = fb[ln];
  const float rs = ws[OFF_RS];
  float fold0 = 1.f, fold1 = 1.f;
  if (ln < 16)      { fold0 = arw[bb * 16 + ln];        fold1 = arw[(bb + 1) * 16 + ln]; }
  else if (ln < 48) { fold0 = rw[bb * 32 + (ln - 16)];  fold1 = rw[(bb + 1) * 32 + (ln - 16)]; }

  float dL0 = wred((z0 - a0) * (z0 - a0));
  float dL1 = wred((z1 - a1) * (z1 - a1));
  float dC0 = wred((z0 - c0) * (z0 - c0));
  float dC1 = wred((z1 - c1) * (z1 - c1));
  float zn0 = wred(z0 * z0);
  float zn1 = wred(z1 * z1);

  const float* plm = ws + OFF_PLm + ln;
  const float* pcm = ws + OFF_PCm + ln;
  float uL0 = plm[64 * 64], uL1 = uL0;
  float uC0 = pcm[64 * 64], uC1 = uC0;
  #pragma unroll 8
  for (int k = 0; k < 64; ++k) {
    float pm = plm[k * 64], pc = pcm[k * 64];
    float zk0 = __shfl(z0, k, 64), zk1 = __shfl(z1, k, 64);
    uL0 = fmaf(zk0, pm, uL0); uL1 = fmaf(zk1, pm, uL1);
    uC0 = fmaf(zk0, pc, uC0); uC1 = fmaf(zk1, pc, uC1);
  }
  float plc = ws[OFF_PLc + ln], pcc = ws[OFF_PCc + ln];
  float plcc = ws[OFF_PLc + 64], pccc = ws[OFF_PCc + 64];
  float sL0 = wred(uL0 * a0 + z0 * plc) + plcc;
  float sL1 = wred(uL1 * a1 + z1 * plc) + plcc;
  float sC0 = wred(uC0 * c0 + z0 * pcc) + pccc;
  float sC1 = wred(uC1 * c1 + z1 * pcc) + pccc;
  float scl0 = sL0 * 0.0625f - dL0, scl1 = sL1 * 0.0625f - dL1;
  float scc0 = sC0 * 0.0625f - dC0, scc1 = sC1 * 0.0625f - dC1;

  const float* ck = ws + OFF_CK2 + ln;
  const float* an = ws + OFF_ANCT + ln;
  float ca0 = ck[64 * 48], ca1 = ca0;
  float za0 = 0.f, za1 = 0.f;
  #pragma unroll 8
  for (int k = 0; k < 64; ++k) {
    float cv = ck[k * 48], av = an[k * 48];
    float zk0 = __shfl(z0, k, 64), zk1 = __shfl(z1, k, 64);
    ca0 = fmaf(zk0, cv, ca0); ca1 = fmaf(zk1, cv, ca1);
    za0 = fmaf(zk0, av, za0); za1 = fmaf(zk1, av, za1);
  }
  float ancn = ws[OFF_ANCN + ln];
  float sc0 = fold0 * ca0 * 0.0625f - (zn0 - 2.f * za0 + ancn);
  float sc1 = fold1 * ca1 * 0.0625f - (zn1 - 2.f * za1 + ancn);
  if (ln == 48) { sc0 = scl0; sc1 = scl1; }
  if (ln == 49) { sc0 = scc0; sc1 = scc1; }
  if (ln > 49)  { sc0 = -1e30f; sc1 = -1e30f; }

  float mx0 = sc0, mx1 = sc1;
  #pragma unroll
  for (int m = 32; m >= 1; m >>= 1) {
    mx0 = fmaxf(mx0, __shfl_xor(mx0, m, 64));
    mx1 = fmaxf(mx1, __shfl_xor(mx1, m, 64));
  }
  float ev0 = (ln < 50) ? __expf(sc0 - mx0) : 0.f;
  float ev1 = (ln < 50) ? __expf(sc1 - mx1) : 0.f;
  float sum0 = wred(ev0), sum1 = wred(ev1);
  float w0 = ev0 * (1.f / sum0) * fold0;
  float w1 = ev1 * (1.f / sum1) * fold1;

  float g0 = 0.f, g1 = 0.f;
  const float* vm = ws + OFF_VM + ln;
  #pragma unroll 8
  for (int s = 0; s < 48; ++s) {
    float vvv = vm[s * 64];
    float s0 = __shfl(w0, s, 64), s1 = __shfl(w1, s, 64);
    g0 = fmaf(s0, vvv, g0); g1 = fmaf(s1, vvv, g1);
  }
  const float* lm = ws + OFF_LM + ln;
  const float* cm = ws + OFF_CM + ln;
  float l0 = lm[64 * 64], l1 = l0;
  float m0 = cm[64 * 64], m1 = m0;
  #pragma unroll 8
  for (int k = 0; k < 64; ++k) {
    float lv = lm[k * 64], cv = cm[k * 64];
    float ak0 = __shfl(a0, k, 64), ak1 = __shfl(a1, k, 64);
    float qk0 = __shfl(c0, k, 64), qk1 = __shfl(c1, k, 64);
    l0 = fmaf(ak0, lv, l0); l1 = fmaf(ak1, lv, l1);
    m0 = fmaf(qk0, cv, m0); m1 = fmaf(qk1, cv, m1);
  }
  float w48_0 = __shfl(w0, 48, 64), w49_0 = __shfl(w0, 49, 64);
  float w48_1 = __shfl(w1, 48, 64), w49_1 = __shfl(w1, 49, 64);
  g0 += w48_0 * l0 + w49_0 * m0;
  g1 += w48_1 * l1 + w49_1 * m1;

  #pragma unroll
  for (int s = 0; s < 2; ++s) {
    float g  = (s == 0) ? g0 : g1;
    float cc = (s == 0) ? cc0 : cc1;
    float ee = (s == 0) ? ee0 : ee1;
    int bbs  = bb + s;
    float gc = wred(g * cc);
    float ge = wred(g * ee);
    float ec = wred(ee * cc);
    float en = wred(ee * ee);
    float fc = wred(fbv * cc);
    float fe = wred(fbv * ee);
    if (ln == 0) {
      float A, Bv;
      if (en > 1e-8f) { float r = ec / en; A = gc - ge * r; Bv = fc - fe * r; }
      else { A = gc; Bv = fc; }
      out[bbs] = A * rs + Bv;
    }
  }
}

extern "C" void kernel_launch(void* const* d_in, const int* in_sizes, int n_in,
                              void* d_out, int out_size, void* d_ws, size_t ws_size,
                              hipStream_t stream) {
  const float* z     = (const float*)d_in[0];
  const float* rw    = (const float*)d_in[1];
  const float* az    = (const float*)d_in[2];
  const float* arw   = (const float*)d_in[3];
  const float* acz   = (const float*)d_in[4];
  const float* ctrl  = (const float*)d_in[5];
  const float* ecov  = (const float*)d_in[6];
  const float* chemb = (const float*)d_in[7];
  const float* chanc = (const float*)d_in[8];
  const float* aemb  = (const float*)d_in[9];
  const float* aanc  = (const float*)d_in[10];
  const float* zW    = (const float*)d_in[11];
  const float* zb    = (const float*)d_in[12];
  const float* latW  = (const float*)d_in[13];
  const float* latb  = (const float*)d_in[14];
  const float* codeW = (const float*)d_in[15];
  const float* codeb = (const float*)d_in[16];
  const float* Wq    = (const float*)d_in[17];
  const float* Wk    = (const float*)d_in[18];
  const float* Wv    = (const float*)d_in[19];
  const float* Wo    = (const float*)d_in[20];
  const float* fW    = (const float*)d_in[21];
  const float* fb    = (const float*)d_in[22];
  float* ws  = (float*)d_ws;
  float* out = (float*)d_out;

  k1a<<<516, 256, 0, stream>>>(chemb, aemb, zW, zb, latW, latb, codeW, codeb,
                               Wq, Wk, Wv, Wo, fW, ws);
  k1b<<<376, 256, 0, stream>>>(latb, codeb, aanc, chanc, ws);
  k2_main<<<512, 256, 0, stream>>>(z, rw, az, arw, acz, ctrl, ecov, fb, ws, out);
}

// Round 13
// 153.691 us; speedup vs baseline: 1.2056x; 1.0087x over previous
//
#include <hip/hip_runtime.h>

// B=4096, D=64, DM=256, K=32, KA=16, S=50
#define PITERS 12

// ---- workspace layout (float offsets) ----
// stage-1 (dead after k1b):
#define OFF_XQ   0        // [65][256]  Zf@Wq
#define OFF_KL   16640    // [65][256]  Lf@Wk
#define OFF_KC   33280    // [65][256]  Cf@Wk
#define OFF_VL   49920    // [65][256]  Lf@Wv
#define OFF_VC   66560    // [65][256]  Cf@Wv
#define OFF_KE   83200    // [48][256]  EMB@Wk
#define OFF_VE   95488    // [48][256]  EMB@Wv
#define OFF_M    107776   // [256][64]  Wo@fW
#define OFF_G    124160   // [64][64]   fW^T fW
// stage-2 (k2 inputs):
#define OFF_PLm  128256   // [65][64]
#define OFF_PLc  132416   // [72]
#define OFF_PCm  132488   // [65][64]
#define OFF_PCc  136648   // [72]
#define OFF_CK2  136720   // [65][48]
#define OFF_ANCT 139840   // [64][48]
#define OFF_ANCN 142912   // [64]
#define OFF_VM   142976   // [48][64]
#define OFF_LM   146048   // [65][64]
#define OFF_CM   150208   // [65][64]
#define OFF_RS   154368   // 1/sigma

__device__ __forceinline__ float wred(float v) {
  #pragma unroll
  for (int m = 32; m >= 1; m >>= 1) v += __shfl_xor(v, m, 64);
  return v;
}

// ===================== K1a (R12-verified): 500 four-row folds + 16 G-tile blocks =====================
__global__ __launch_bounds__(256)
void k1a(const float* __restrict__ chemb, const float* __restrict__ aemb,
         const float* __restrict__ zW, const float* __restrict__ zb,
         const float* __restrict__ latW, const float* __restrict__ latb,
         const float* __restrict__ codeW, const float* __restrict__ codeb,
         const float* __restrict__ Wq, const float* __restrict__ Wk,
         const float* __restrict__ Wv, const float* __restrict__ Wo,
         const float* __restrict__ fW, float* __restrict__ ws) {
  __shared__ __align__(16) float red[1024];
  const int t = threadIdx.x, b = blockIdx.x;
  const int j = t & 63, ks = t >> 6;

  const float *a0p, *a1p, *a2p, *a3p;
  const float* Bm;
  int bstride = 256, jbase = 0;
  int d0, d1, d2, d3;
  bool gpath = false;

  if (b < 340) {                        // W5: rows 0..64 (row 64 = bias)
    int u = b / 68, r2 = b - u * 68;
    int rg = r2 >> 2, jc = r2 & 3; jbase = jc * 64;
    const float *Wmat, *bias;
    if (u == 0)      { Wmat = zW;    bias = zb;    Bm = Wq; }
    else if (u == 1) { Wmat = latW;  bias = latb;  Bm = Wk; }
    else if (u == 2) { Wmat = codeW; bias = codeb; Bm = Wk; }
    else if (u == 3) { Wmat = latW;  bias = latb;  Bm = Wv; }
    else             { Wmat = codeW; bias = codeb; Bm = Wv; }
    int r0 = rg * 4;
    int rr1 = r0 + 1, rr2 = r0 + 2, rr3 = r0 + 3;
    a0p = (r0 < 64) ? (Wmat + r0 * 256) : bias;
    a1p = (rr1 < 64) ? (Wmat + rr1 * 256) : bias;
    a2p = (rr2 < 64) ? (Wmat + rr2 * 256) : bias;
    a3p = (rr3 < 64) ? (Wmat + rr3 * 256) : bias;
    d0 = u * 16640 + r0 * 256 + jbase;
    d1 = (rr1 <= 64) ? (u * 16640 + rr1 * 256 + jbase) : -1;
    d2 = (rr2 <= 64) ? (u * 16640 + rr2 * 256 + jbase) : -1;
    d3 = (rr3 <= 64) ? (u * 16640 + rr3 * 256 + jbase) : -1;
  } else if (b < 436) {                 // KE/VE: 48 rows each
    int b2 = b - 340; int isV = (b2 >= 48); int rr = b2 - (isV ? 48 : 0);
    int rg = rr >> 2, jc = rr & 3; jbase = jc * 64;
    Bm = isV ? Wv : Wk;
    int base = isV ? OFF_VE : OFF_KE;
    int s0 = rg * 4;
    a0p = (s0 + 0 < 16) ? (aemb + (s0 + 0) * 256) : (chemb + (s0 + 0 - 16) * 256);
    a1p = (s0 + 1 < 16) ? (aemb + (s0 + 1) * 256) : (chemb + (s0 + 1 - 16) * 256);
    a2p = (s0 + 2 < 16) ? (aemb + (s0 + 2) * 256) : (chemb + (s0 + 2 - 16) * 256);
    a3p = (s0 + 3 < 16) ? (aemb + (s0 + 3) * 256) : (chemb + (s0 + 3 - 16) * 256);
    d0 = base + (s0 + 0) * 256 + jbase;
    d1 = base + (s0 + 1) * 256 + jbase;
    d2 = base + (s0 + 2) * 256 + jbase;
    d3 = base + (s0 + 3) * 256 + jbase;
  } else if (b < 500) {                 // M = Wo @ fW
    int i0 = (b - 436) * 4;
    Bm = fW; bstride = 64;
    a0p = Wo + (i0 + 0) * 256; a1p = Wo + (i0 + 1) * 256;
    a2p = Wo + (i0 + 2) * 256; a3p = Wo + (i0 + 3) * 256;
    d0 = OFF_M + (i0 + 0) * 64; d1 = OFF_M + (i0 + 1) * 64;
    d2 = OFF_M + (i0 + 2) * 64; d3 = OFF_M + (i0 + 3) * 64;
  } else {                              // G = fW^T fW (A = columns of fW, K=256 via 4 ks groups)
    gpath = true;
    int i0 = (b - 500) * 4;
    Bm = fW; bstride = 64;
    a0p = fW + i0 + 0; a1p = fW + i0 + 1; a2p = fW + i0 + 2; a3p = fW + i0 + 3;
    d0 = OFF_G + (i0 + 0) * 64; d1 = OFF_G + (i0 + 1) * 64;
    d2 = OFF_G + (i0 + 2) * 64; d3 = OFF_G + (i0 + 3) * 64;
  }

  float acc0 = 0.f, acc1 = 0.f, acc2 = 0.f, acc3 = 0.f;
  const float* bp = Bm + (ks * 64) * bstride + jbase + j;
  if (!gpath) {
    const float* a0 = a0p + ks * 64;
    const float* a1 = a1p + ks * 64;
    const float* a2 = a2p + ks * 64;
    const float* a3 = a3p + ks * 64;
    #pragma unroll 4
    for (int k4 = 0; k4 < 16; ++k4) {
      float b0 = bp[(k4 * 4 + 0) * bstride];
      float b1 = bp[(k4 * 4 + 1) * bstride];
      float b2 = bp[(k4 * 4 + 2) * bstride];
      float b3 = bp[(k4 * 4 + 3) * bstride];
      float4 x0 = *(const float4*)(a0 + k4 * 4);
      float4 x1 = *(const float4*)(a1 + k4 * 4);
      float4 x2 = *(const float4*)(a2 + k4 * 4);
      float4 x3 = *(const float4*)(a3 + k4 * 4);
      acc0 += x0.x * b0 + x0.y * b1 + x0.z * b2 + x0.w * b3;
      acc1 += x1.x * b0 + x1.y * b1 + x1.z * b2 + x1.w * b3;
      acc2 += x2.x * b0 + x2.y * b1 + x2.z * b2 + x2.w * b3;
      acc3 += x3.x * b0 + x3.y * b1 + x3.z * b2 + x3.w * b3;
    }
  } else {
    const float* a0 = a0p + (ks * 64) * 64;
    const float* a1 = a1p + (ks * 64) * 64;
    const float* a2 = a2p + (ks * 64) * 64;
    const float* a3 = a3p + (ks * 64) * 64;
    #pragma unroll 4
    for (int k = 0; k < 64; ++k) {
      float bv = bp[k * bstride];
      acc0 += a0[k * 64] * bv;
      acc1 += a1[k * 64] * bv;
      acc2 += a2[k * 64] * bv;
      acc3 += a3[k * 64] * bv;
    }
  }
  red[0 * 256 + t] = acc0;
  red[1 * 256 + t] = acc1;
  red[2 * 256 + t] = acc2;
  red[3 * 256 + t] = acc3;
  __syncthreads();
  if (t < 64) {
    if (d0 >= 0) ws[d0 + t] = (red[t] + red[64 + t]) + (red[128 + t] + red[192 + t]);
    if (d1 >= 0) ws[d1 + t] = (red[256 + t] + red[320 + t]) + (red[384 + t] + red[448 + t]);
    if (d2 >= 0) ws[d2 + t] = (red[512 + t] + red[576 + t]) + (red[640 + t] + red[704 + t]);
    if (d3 >= 0) ws[d3 + t] = (red[768 + t] + red[832 + t]) + (red[896 + t] + red[960 + t]);
  }
}

// ===================== K1b: 375 pairwise folds + sigma (block 375) =====================
__global__ __launch_bounds__(256)
void k1b(const float* __restrict__ latb, const float* __restrict__ codeb,
         const float* __restrict__ aanc, const float* __restrict__ chanc,
         float* __restrict__ ws) {
  __shared__ __align__(16) float sm[13120];   // sigma uses all; fold blocks use first 256
  const int t = threadIdx.x, q = blockIdx.x;

  if (q == 375) {
    // ---- sigma: G from ws, 3 tiled trace-normed squarings -> G^8,
    // ----        12 single-wave power iters (G^96 total, R7-proven level), Rayleigh on G ----
    const int ln = t & 63;
    float* bufA = sm;            // ping
    float* G0   = sm + 4352;     // raw G for Rayleigh
    float* bufB = sm + 8704;     // pong
    float* red  = sm + 13056;    // [64] scratch
    {
      float tv = (t < 64) ? ws[OFF_G + t * 65] : 0.f;   // diag
      tv = wred(tv);
      if (t == 0) red[0] = (tv > 0.f) ? 1.f / tv : 0.f;
    }
    __syncthreads();
    {
      float inv0 = red[0];
      for (int e = t; e < 4096; e += 256) {
        int i = e >> 6, jj = e & 63;
        float g = ws[OFF_G + e];
        G0[i * 68 + jj]   = g;
        bufA[i * 68 + jj] = g * inv0;
      }
    }
    __syncthreads();
    const int ty = t >> 4, tx = t & 15;
    const int i0 = ty * 4, j0 = tx * 4;
    float* src = bufA;
    float* dst = bufB;
    for (int sq = 0; sq < 3; ++sq) {           // H <- H^2 / tr(H^2); symmetric
      float acc[4][4];
      #pragma unroll
      for (int i = 0; i < 4; ++i)
        #pragma unroll
        for (int j = 0; j < 4; ++j) acc[i][j] = 0.f;
      #pragma unroll 4
      for (int k4 = 0; k4 < 16; ++k4) {
        float4 av[4], bv[4];
        #pragma unroll
        for (int i = 0; i < 4; ++i) av[i] = *(const float4*)&src[(i0 + i) * 68 + k4 * 4];
        #pragma unroll
        for (int j = 0; j < 4; ++j) bv[j] = *(const float4*)&src[(j0 + j) * 68 + k4 * 4];
        #pragma unroll
        for (int i = 0; i < 4; ++i)
          #pragma unroll
          for (int j = 0; j < 4; ++j)
            acc[i][j] += av[i].x * bv[j].x + av[i].y * bv[j].y + av[i].z * bv[j].z + av[i].w * bv[j].w;
      }
      if (ty == tx) red[ty] = acc[0][0] + acc[1][1] + acc[2][2] + acc[3][3];
      __syncthreads();
      {
        float tr = 0.f;
        #pragma unroll
        for (int x = 0; x < 16; ++x) tr += red[x];
        float inv = (tr > 0.f) ? 1.f / tr : 0.f;
        #pragma unroll
        for (int i = 0; i < 4; ++i)
          *(float4*)&dst[(i0 + i) * 68 + j0] = make_float4(acc[i][0] * inv, acc[i][1] * inv,
                                                           acc[i][2] * inv, acc[i][3] * inv);
      }
      __syncthreads();
      float* tmp = src; src = dst; dst = tmp;
    }
    // src = G^8 (normalized). Single-wave power iteration + Rayleigh on G0.
    if (t < 64) {
      float4 h[16];
      #pragma unroll
      for (int k4 = 0; k4 < 16; ++k4) h[k4] = *(const float4*)&src[ln * 68 + k4 * 4];
      float rn = 0.f;
      #pragma unroll
      for (int k4 = 0; k4 < 16; ++k4)
        rn += h[k4].x * h[k4].x + h[k4].y * h[k4].y + h[k4].z * h[k4].z + h[k4].w * h[k4].w;
      float bnv = rn; int bj = ln;
      #pragma unroll
      for (int m = 32; m >= 1; m >>= 1) {
        float ov = __shfl_xor(bnv, m, 64);
        int   oj = __shfl_xor(bj, m, 64);
        if (ov > bnv || (ov == bnv && oj < bj)) { bnv = ov; bj = oj; }
      }
      float v = src[bj * 68 + ln];               // column bj (= row bj, symmetric)
      for (int pi = 0; pi < PITERS; ++pi) {
        red[ln] = v;
        float y0 = 0.f, y1 = 0.f, y2 = 0.f, y3 = 0.f;
        #pragma unroll
        for (int k4 = 0; k4 < 16; ++k4) {
          float4 vvv = *(const float4*)&red[k4 * 4];
          y0 = fmaf(h[k4].x, vvv.x, y0);
          y1 = fmaf(h[k4].y, vvv.y, y1);
          y2 = fmaf(h[k4].z, vvv.z, y2);
          y3 = fmaf(h[k4].w, vvv.w, y3);
        }
        float y = (y0 + y1) + (y2 + y3);
        float n2 = wred(y * y);
        v = (n2 > 0.f) ? y * rsqrtf(n2) : 0.f;
      }
      red[ln] = v;
      float y0 = 0.f, y1 = 0.f, y2 = 0.f, y3 = 0.f;
      #pragma unroll
      for (int k4 = 0; k4 < 16; ++k4) {
        float4 gg = *(const float4*)&G0[ln * 68 + k4 * 4];
        float4 vvv = *(const float4*)&red[k4 * 4];
        y0 = fmaf(gg.x, vvv.x, y0);
        y1 = fmaf(gg.y, vvv.y, y1);
        y2 = fmaf(gg.z, vvv.z, y2);
        y3 = fmaf(gg.w, vvv.w, y3);
      }
      float y = (y0 + y1) + (y2 + y3);
      float num = wred(v * y), den = wred(v * v);
      if (ln == 0) {
        float lam = (den > 1e-37f) ? num / den : 0.f;
        lam = fmaxf(lam, 0.f);
        ws[OFF_RS] = 1.f / fmaxf(sqrtf(lam), 1e-8f);
      }
    }
    return;
  }

  // ---- fold units (R12-verified) ----
  float* red = sm;
  if (q == 374) {                 // ANCT [64 d][48 s] + ANCN
    for (int e = t; e < 3072; e += 256) {
      int d = e / 48, s = e - d * 48;
      const float* a = (s < 16) ? (aanc + s * 64) : (chanc + (s - 16) * 64);
      ws[OFF_ANCT + e] = a[d];
    }
    if (t < 64) {
      float n = 0.f;
      if (t < 48) {
        const float* a = (t < 16) ? (aanc + t * 64) : (chanc + (t - 16) * 64);
        #pragma unroll 4
        for (int d = 0; d < 64; ++d) n += a[d] * a[d];
      }
      ws[OFF_ANCN + t] = n;
    }
    return;
  }
  if (q == 373) {                 // PLc[r] = XQ[r]·KL[64] ; PCc[r] = XQ[r]·KC[64]
    if (t < 65) {
      const float* ap = ws + OFF_XQ + t * 256;
      const float* bp = ws + OFF_KL + 64 * 256;
      float acc = 0.f;
      #pragma unroll 4
      for (int e = 0; e < 256; ++e) acc += ap[e] * bp[e];
      ws[OFF_PLc + t] = acc;
    } else if (t >= 128 && t < 193) {
      int r = t - 128;
      const float* ap = ws + OFF_XQ + r * 256;
      const float* bp = ws + OFF_KC + 64 * 256;
      float acc = 0.f;
      #pragma unroll 4
      for (int e = 0; e < 256; ++e) acc += ap[e] * bp[e];
      ws[OFF_PCc + r] = acc;
    }
    return;
  }

  const int j = t & 63, ks = t >> 6;
  const float* ap; const float* bp;
  int bstride, dstBase, nout = 64;
  if (q < 325) {
    int g = q / 65, r = q - g * 65;
    const float* A = ws + ((g < 3) ? OFF_XQ : (g == 3 ? OFF_VL : OFF_VC)) + r * 256;
    if (g == 0)      { bp = ws + OFF_KL + j * 256 + ks * 64; bstride = 1; dstBase = OFF_PLm + r * 64; }
    else if (g == 1) { bp = ws + OFF_KC + j * 256 + ks * 64; bstride = 1; dstBase = OFF_PCm + r * 64; }
    else if (g == 2) { int jj = (j < 48) ? j : 47;
                       bp = ws + OFF_KE + jj * 256 + ks * 64; bstride = 1; dstBase = OFF_CK2 + r * 48; nout = 48; }
    else if (g == 3) { bp = ws + OFF_M + (ks * 64) * 64 + j; bstride = 64; dstBase = OFF_LM + r * 64; }
    else             { bp = ws + OFF_M + (ks * 64) * 64 + j; bstride = 64; dstBase = OFF_CM + r * 64; }
    ap = A + ks * 64;
  } else {                        // VM[s] = VE[s]@M
    int s = q - 325;
    ap = ws + OFF_VE + s * 256 + ks * 64;
    bp = ws + OFF_M + (ks * 64) * 64 + j; bstride = 64;
    dstBase = OFF_VM + s * 64;
  }
  float a0 = 0.f, a1 = 0.f, a2 = 0.f, a3 = 0.f;
  #pragma unroll 4
  for (int k = 0; k < 64; k += 4) {
    a0 += ap[k + 0] * bp[(k + 0) * bstride];
    a1 += ap[k + 1] * bp[(k + 1) * bstride];
    a2 += ap[k + 2] * bp[(k + 2) * bstride];
    a3 += ap[k + 3] * bp[(k + 3) * bstride];
  }
  red[t] = (a0 + a1) + (a2 + a3);
  __syncthreads();
  if (t < nout) ws[dstBase + t] = red[t] + red[64 + t] + red[128 + t] + red[192 + t];
}

// ===================== K2: wave-per-2-batches, LDS-broadcast matvecs; writes out =====================
__global__ __launch_bounds__(256)
void k2_main(const float* __restrict__ z, const float* __restrict__ rw,
             const float* __restrict__ az, const float* __restrict__ arw,
             const float* __restrict__ acz, const float* __restrict__ ctrl,
             const float* __restrict__ ecov, const float* __restrict__ fb,
             const float* __restrict__ ws, float* __restrict__ out) {
  __shared__ __align__(16) float sm[2048];   // 4 waves x 512 floats broadcast staging
  const int t = threadIdx.x;
  const int wv = t >> 6, ln = t & 63;
  float* wsm = sm + wv * 512;   // z0:0 z1:64 a0:128 a1:192 c0:256 c1:320 w0:384 w1:448

  const int bb = blockIdx.x * 8 + wv * 2;
  float z0 = z[bb * 64 + ln],        z1 = z[(bb + 1) * 64 + ln];
  float a0 = az[bb * 64 + ln],       a1 = az[(bb + 1) * 64 + ln];
  float c0 = acz[bb * 64 + ln],      c1 = acz[(bb + 1) * 64 + ln];
  float cc0 = ctrl[bb * 64 + ln],    cc1 = ctrl[(bb + 1) * 64 + ln];
  float ee0 = ecov[bb * 64 + ln],    ee1 = ecov[(bb + 1) * 64 + ln];
  float fbv = fb[ln];
  const float rs = ws[OFF_RS];
  float fold0 = 1.f, fold1 = 1.f;
  if (ln < 16)      { fold0 = arw[bb * 16 + ln];        fold1 = arw[(bb + 1) * 16 + ln]; }
  else if (ln < 48) { fold0 = rw[bb * 32 + (ln - 16)];  fold1 = rw[(bb + 1) * 32 + (ln - 16)]; }

  // stage broadcast vectors (same-wave DS write->read: in-order, compiler inserts lgkmcnt)
  wsm[ln]        = z0;  wsm[64 + ln]  = z1;
  wsm[128 + ln]  = a0;  wsm[192 + ln] = a1;
  wsm[256 + ln]  = c0;  wsm[320 + ln] = c1;

  float dL0 = wred((z0 - a0) * (z0 - a0));
  float dL1 = wred((z1 - a1) * (z1 - a1));
  float dC0 = wred((z0 - c0) * (z0 - c0));
  float dC1 = wred((z1 - c1) * (z1 - c1));
  float zn0 = wred(z0 * z0);
  float zn1 = wred(z1 * z1);

  // merged PL/PC + chart loops: one z-broadcast float4 feeds 8 FMA pairs
  const float* plm = ws + OFF_PLm + ln;
  const float* pcm = ws + OFF_PCm + ln;
  const float* ck = ws + OFF_CK2 + ln;
  const float* an = ws + OFF_ANCT + ln;
  float uL0 = plm[64 * 64], uL1 = uL0;
  float uC0 = pcm[64 * 64], uC1 = uC0;
  float ca0 = ck[64 * 48], ca1 = ca0;
  float za0 = 0.f, za1 = 0.f;
  #pragma unroll 4
  for (int k4 = 0; k4 < 16; ++k4) {
    float4 zk0 = *(const float4*)&wsm[k4 * 4];
    float4 zk1 = *(const float4*)&wsm[64 + k4 * 4];
    #define K2_STEP(comp, kk)                                            \
      { int k = (kk);                                                    \
        float pm = plm[k * 64], pc = pcm[k * 64];                        \
        float cv = ck[k * 48],  av = an[k * 48];                         \
        uL0 = fmaf(zk0.comp, pm, uL0); uL1 = fmaf(zk1.comp, pm, uL1);    \
        uC0 = fmaf(zk0.comp, pc, uC0); uC1 = fmaf(zk1.comp, pc, uC1);    \
        ca0 = fmaf(zk0.comp, cv, ca0); ca1 = fmaf(zk1.comp, cv, ca1);    \
        za0 = fmaf(zk0.comp, av, za0); za1 = fmaf(zk1.comp, av, za1); }
    K2_STEP(x, k4 * 4 + 0)
    K2_STEP(y, k4 * 4 + 1)
    K2_STEP(z, k4 * 4 + 2)
    K2_STEP(w, k4 * 4 + 3)
    #undef K2_STEP
  }
  float plc = ws[OFF_PLc + ln], pcc = ws[OFF_PCc + ln];
  float plcc = ws[OFF_PLc + 64], pccc = ws[OFF_PCc + 64];
  float sL0 = wred(uL0 * a0 + z0 * plc) + plcc;
  float sL1 = wred(uL1 * a1 + z1 * plc) + plcc;
  float sC0 = wred(uC0 * c0 + z0 * pcc) + pccc;
  float sC1 = wred(uC1 * c1 + z1 * pcc) + pccc;
  float scl0 = sL0 * 0.0625f - dL0, scl1 = sL1 * 0.0625f - dL1;
  float scc0 = sC0 * 0.0625f - dC0, scc1 = sC1 * 0.0625f - dC1;

  float ancn = ws[OFF_ANCN + ln];
  float sc0 = fold0 * ca0 * 0.0625f - (zn0 - 2.f * za0 + ancn);
  float sc1 = fold1 * ca1 * 0.0625f - (zn1 - 2.f * za1 + ancn);
  if (ln == 48) { sc0 = scl0; sc1 = scl1; }
  if (ln == 49) { sc0 = scc0; sc1 = scc1; }
  if (ln > 49)  { sc0 = -1e30f; sc1 = -1e30f; }

  // softmax over 50 + fold routing weights
  float mx0 = sc0, mx1 = sc1;
  #pragma unroll
  for (int m = 32; m >= 1; m >>= 1) {
    mx0 = fmaxf(mx0, __shfl_xor(mx0, m, 64));
    mx1 = fmaxf(mx1, __shfl_xor(mx1, m, 64));
  }
  float ev0 = (ln < 50) ? __expf(sc0 - mx0) : 0.f;
  float ev1 = (ln < 50) ? __expf(sc1 - mx1) : 0.f;
  float sum0 = wred(ev0), sum1 = wred(ev1);
  float w0 = ev0 * (1.f / sum0) * fold0;
  float w1 = ev1 * (1.f / sum1) * fold1;
  wsm[384 + ln] = w0;
  wsm[448 + ln] = w1;

  // g: chart part via w-broadcast float4 (12 x 4 charts)
  float g0 = 0.f, g1 = 0.f;
  const float* vm = ws + OFF_VM + ln;
  #pragma unroll 4
  for (int s4 = 0; s4 < 12; ++s4) {
    float4 w40 = *(const float4*)&wsm[384 + s4 * 4];
    float4 w41 = *(const float4*)&wsm[448 + s4 * 4];
    float v0 = vm[(s4 * 4 + 0) * 64];
    float v1 = vm[(s4 * 4 + 1) * 64];
    float v2 = vm[(s4 * 4 + 2) * 64];
    float v3 = vm[(s4 * 4 + 3) * 64];
    g0 += w40.x * v0 + w40.y * v1 + w40.z * v2 + w40.w * v3;
    g1 += w41.x * v0 + w41.y * v1 + w41.z * v2 + w41.w * v3;
  }

  // lat/code part: merged LM/CM loop with a/c broadcasts
  const float* lm = ws + OFF_LM + ln;
  const float* cm = ws + OFF_CM + ln;
  float l0 = lm[64 * 64], l1 = l0;
  float m0 = cm[64 * 64], m1 = m0;
  #pragma unroll 4
  for (int k4 = 0; k4 < 16; ++k4) {
    float4 ak0 = *(const float4*)&wsm[128 + k4 * 4];
    float4 ak1 = *(const float4*)&wsm[192 + k4 * 4];
    float4 qk0 = *(const float4*)&wsm[256 + k4 * 4];
    float4 qk1 = *(const float4*)&wsm[320 + k4 * 4];
    #define K2_STEP2(comp, kk)                                           \
      { int k = (kk);                                                    \
        float lv = lm[k * 64], cv2 = cm[k * 64];                         \
        l0 = fmaf(ak0.comp, lv, l0); l1 = fmaf(ak1.comp, lv, l1);        \
        m0 = fmaf(qk0.comp, cv2, m0); m1 = fmaf(qk1.comp, cv2, m1); }
    K2_STEP2(x, k4 * 4 + 0)
    K2_STEP2(y, k4 * 4 + 1)
    K2_STEP2(z, k4 * 4 + 2)
    K2_STEP2(w, k4 * 4 + 3)
    #undef K2_STEP2
  }
  float w48_0 = wsm[384 + 48], w49_0 = wsm[384 + 49];
  float w48_1 = wsm[448 + 48], w49_1 = wsm[448 + 49];
  g0 += w48_0 * l0 + w49_0 * m0;
  g1 += w48_1 * l1 + w49_1 * m1;

  // epilogue: projections off exact covector; out = A*rs + B
  #pragma unroll
  for (int s = 0; s < 2; ++s) {
    float g  = (s == 0) ? g0 : g1;
    float cc = (s == 0) ? cc0 : cc1;
    float ee = (s == 0) ? ee0 : ee1;
    int bbs  = bb + s;
    float gc = wred(g * cc);
    float ge = wred(g * ee);
    float ec = wred(ee * cc);
    float en = wred(ee * ee);
    float fc = wred(fbv * cc);
    float fe = wred(fbv * ee);
    if (ln == 0) {
      float A, Bv;
      if (en > 1e-8f) { float r = ec / en; A = gc - ge * r; Bv = fc - fe * r; }
      else { A = gc; Bv = fc; }
      out[bbs] = A * rs + Bv;
    }
  }
}

extern "C" void kernel_launch(void* const* d_in, const int* in_sizes, int n_in,
                              void* d_out, int out_size, void* d_ws, size_t ws_size,
                              hipStream_t stream) {
  const float* z     = (const float*)d_in[0];
  const float* rw    = (const float*)d_in[1];
  const float* az    = (const float*)d_in[2];
  const float* arw   = (const float*)d_in[3];
  const float* acz   = (const float*)d_in[4];
  const float* ctrl  = (const float*)d_in[5];
  const float* ecov  = (const float*)d_in[6];
  const float* chemb = (const float*)d_in[7];
  const float* chanc = (const float*)d_in[8];
  const float* aemb  = (const float*)d_in[9];
  const float* aanc  = (const float*)d_in[10];
  const float* zW    = (const float*)d_in[11];
  const float* zb    = (const float*)d_in[12];
  const float* latW  = (const float*)d_in[13];
  const float* latb  = (const float*)d_in[14];
  const float* codeW = (const float*)d_in[15];
  const float* codeb = (const float*)d_in[16];
  const float* Wq    = (const float*)d_in[17];
  const float* Wk    = (const float*)d_in[18];
  const float* Wv    = (const float*)d_in[19];
  const float* Wo    = (const float*)d_in[20];
  const float* fW    = (const float*)d_in[21];
  const float* fb    = (const float*)d_in[22];
  float* ws  = (float*)d_ws;
  float* out = (float*)d_out;

  k1a<<<516, 256, 0, stream>>>(chemb, aemb, zW, zb, latW, latb, codeW, codeb,
                               Wq, Wk, Wv, Wo, fW, ws);
  k1b<<<376, 256, 0, stream>>>(latb, codeb, aanc, chanc, ws);
  k2_main<<<512, 256, 0, stream>>>(z, rw, az, arw, acz, ctrl, ecov, fb, ws, out);
}